// Round 11
// baseline (22830.447 us; speedup 1.0000x reference)
//
#include <hip/hip_runtime.h>
#include <cstdint>
#include <cstddef>
#include <cstring>

using u32 = unsigned int;
typedef _Float16 h2 __attribute__((ext_vector_type(2)));
typedef _Float16 h4 __attribute__((ext_vector_type(4)));
typedef _Float16 h8 __attribute__((ext_vector_type(8)));
typedef float f32x4 __attribute__((ext_vector_type(4)));

constexpr int B_=64, T_=600, U_=50, V_=77, H_=400, OUT_=121;
constexpr int G1=50, GPA=16, G2=50, G3=50, GOUT=8;
constexpr int NBLK = G1+GPA+G2+G3+GOUT; // 174

// ---- ws byte offsets ----
constexpr size_t FLAGS_B = 0;                        // [stage4][t600][prod64] 16B slots
constexpr size_t FLAGS_SZ = 4ull*600*64*16;          // 2,457,600
// MFMA weight packs: [ks][row32][q4][i8] f16, row = unit_local*4 + gate
constexpr size_t W1WG   = 15ull*32*4*8;              // 15360 f16 (K=480)
constexpr size_t W1F_B  = FLAGS_SZ;
constexpr size_t W2WG   = 28ull*32*4*8;              // 28672 f16 (K=896 padded)
constexpr size_t W2F_B  = W1F_B + 50ull*W1WG*2;
constexpr size_t W3F_B  = W2F_B + 50ull*W2WG*2;
constexpr size_t WOWG   = 300ull*32*16;
constexpr size_t WOF_B  = W3F_B + 50ull*W2WG*2;
constexpr size_t WWFWG  = 200ull*32;                 // u32
constexpr size_t WWF_B  = WOF_B + 8ull*WOWG*2;
// mix MFMA packs for L1 in-block window: 50 × [ks15][row32][q4][i8]
constexpr size_t WWMWG  = 15ull*32*4*8;              // 15360 f16
constexpr size_t WWM_B  = WWF_B + 16ull*WWFWG*4;
// write-once, t-indexed inter-stage buffers (consumers: NONTEMPORAL loads)
constexpr size_t FWV_B  = WWM_B + 50ull*WWMWG*2;     // u32 [600][64][40]
constexpr size_t FH1_B  = FWV_B + 600ull*64*40*4;    // u32 [600][64][200]
constexpr size_t FH2_B  = FH1_B + 600ull*64*200*4;
constexpr size_t FH3_B  = FH2_B + 600ull*64*200*4;
// total ~112 MB

// LDS strides (f16 units) — 16B-aligned rows for ds_read_b128 B-fragments
constexpr int SW1 = 184;   // L1 panels (160 dims used, 92 u32 pairs)
constexpr int SW2 = 232;   // L2/L3 panels (224 dims used, 116 u32 pairs)
constexpr int SWO = 244;   // OUT (240 dims)
constexpr int SMEM_BYTES = 59392;   // L2 panels: 2*64*232*2
// L1 LDS layout: panA @0 (23552), panB @23552 (23552), kapS f32[640] @47104 (2560),
//                mixE f32[64][32] @49664 (8192); wvs f32[64][77] overlays panB

struct P {
  const float *x, *tmask, *h0, *c0, *pwv, *pkap;
  const int *text;
  const float *wih1,*whh1,*bih1,*bhh1;
  const float *wih2,*whh2,*bih2,*bhh2;
  const float *wih3,*whh3,*bih3,*bhh3;
  const float *wwin,*bwin,*wout,*bout;
  float *out_y,*out_wv,*out_kap;
  _Float16 *w1f,*w2f,*w3f,*wof,*wwm;
  u32 *wwf;
  u32 *fwv,*fh1,*fh2,*fh3;
  u32 *flags;
};

__device__ __forceinline__ u32 ldc_u(const u32* p) {
  return __hip_atomic_load((u32*)p, __ATOMIC_RELAXED, __HIP_MEMORY_SCOPE_AGENT);
}
__device__ __forceinline__ void stc_u(u32* p, u32 v) {
  __hip_atomic_store(p, v, __ATOMIC_RELAXED, __HIP_MEMORY_SCOPE_AGENT);
}
// nontemporal load for write-once streaming buffers: don't evict weight packs from L2
__device__ __forceinline__ u32 ldnt(const u32* p) {
  return __builtin_nontemporal_load(p);
}
__device__ __forceinline__ float sigm(float x) { return 1.f/(1.f+__expf(-x)); }
__device__ __forceinline__ h2 pk16(float a, float b) {
  auto t = __builtin_amdgcn_cvt_pkrtz(a, b);
  h2 r; memcpy(&r, &t, 4); return r;
}
__device__ __forceinline__ u32 h2u(h2 v) { u32 r; memcpy(&r, &v, 4); return r; }
__device__ __forceinline__ h2 u2h(u32 v) { h2 r; memcpy(&r, &v, 4); return r; }
__device__ __forceinline__ u32 pkf(float a, float b) { return h2u(pk16(a, b)); }
__device__ __forceinline__ float dot2(h2 a, h2 b, float c) { return __builtin_amdgcn_fdot2(a, b, c, false); }
__device__ __forceinline__ h2 lo4(h4 v) { return __builtin_shufflevector(v, v, 0, 1); }
__device__ __forceinline__ h2 hi4(h4 v) { return __builtin_shufflevector(v, v, 2, 3); }

// ---- parallel per-producer flags (R9 proven form): n spinners, s_sleep backoff ----
__device__ __forceinline__ void wait_flags(u32* f, int stage, int t, int n) {
  if ((int)threadIdx.x < n) {
    const u32* s = f + (((size_t)stage*600 + t)*64 + threadIdx.x)*4;   // 16B slots
    while (ldc_u(s) == 0) __builtin_amdgcn_s_sleep(2);
  }
  __syncthreads();
}
__device__ __forceinline__ void set_flag(u32* f, int stage, int t, int prod) {
  if (threadIdx.x == 0)
    stc_u(f + (((size_t)stage*600 + t)*64 + prod)*4, 1u);
}

// ---- MFMA chunk: wave w computes 2 C-tiles (16 rows x 16 batches each) over KS k-steps
__device__ __forceinline__ void mfma_chunk5(const _Float16* pan, int SWf, const _Float16* WA,
                                            int w, int l, f32x4& acc0, f32x4& acc1) {
  const _Float16* bp0 = pan + ((w>>1)*32 + (l&15))*SWf + (l>>4)*8;
  const _Float16* bp1 = bp0 + 16*SWf;
  const _Float16* ap  = WA + (((16*(w&1) + (l&15))*4) + (l>>4))*8;
#pragma unroll
  for (int ks = 0; ks < 5; ++ks) {
    h8 a  = *(const h8*)(ap  + ks*1024);
    h8 b0 = *(const h8*)(bp0 + ks*32);
    h8 b1 = *(const h8*)(bp1 + ks*32);
    acc0 = __builtin_amdgcn_mfma_f32_16x16x32_f16(a, b0, acc0, 0, 0, 0);
    acc1 = __builtin_amdgcn_mfma_f32_16x16x32_f16(a, b1, acc1, 0, 0, 0);
  }
}
__device__ __forceinline__ void mfma_chunk7(const _Float16* pan, int SWf, const _Float16* WA,
                                            int w, int l, f32x4& acc0, f32x4& acc1) {
  const _Float16* bp0 = pan + ((w>>1)*32 + (l&15))*SWf + (l>>4)*8;
  const _Float16* bp1 = bp0 + 16*SWf;
  const _Float16* ap  = WA + (((16*(w&1) + (l&15))*4) + (l>>4))*8;
#pragma unroll
  for (int ks = 0; ks < 7; ++ks) {
    h8 a  = *(const h8*)(ap  + ks*1024);
    h8 b0 = *(const h8*)(bp0 + ks*32);
    h8 b1 = *(const h8*)(bp1 + ks*32);
    acc0 = __builtin_amdgcn_mfma_f32_16x16x32_f16(a, b0, acc0, 0, 0, 0);
    acc1 = __builtin_amdgcn_mfma_f32_16x16x32_f16(a, b1, acc1, 0, 0, 0);
  }
}

// ================= L1 (self-sufficient: in-block window via MFMA on staged panels) =================
__device__ void lstm1_role(const P& p, int wg, char* smem) {
  const int tid = threadIdx.x;
  const int w = tid >> 6, l = tid & 63;
  const int ul = (w&1)*4 + (l>>4);           // unit_local 0..7
  const int u  = wg*8 + ul;
  const int bA = (w>>1)*32 + (l&15), bB = bA + 16;
  _Float16* panA = (_Float16*)smem;
  _Float16* panB = panA + 64*SW1;
  float* kapS = (float*)(smem + 47104);      // [64][10] persistent kappa
  float* mixE = (float*)(smem + 49664);      // [64][32] exp(mix)
  float* wvs  = (float*)(smem + 23552);      // overlay panB: [64][77] f32
  _Float16* wgW = p.w1f + (size_t)wg * W1WG;
  _Float16* wgM = p.wwm + (size_t)wg * WWMWG;
  // gate pack [ks15][row32][q4][i8]; row = cu*4+g; K-order [rec400 | wv77 | x3]
  for (int e = tid; e < 15360; e += 256) {
    int i = e & 7, q = (e>>3)&3, row = (e>>5)&31, ks = e>>10;
    int k = ks*32 + q*8 + i;
    int cu = row>>2, g = row&3;
    int r = g*400 + wg*8 + cu;
    float v;
    if (k < 400)      v = p.whh1[(size_t)r*400 + k];
    else if (k < 477) v = p.wih1[(size_t)r*80 + 3 + (k-400)];
    else              v = p.wih1[(size_t)r*80 + (k-477)];
    wgW[e] = (_Float16)v;
  }
  // mix pack: row = m (30 used), K-order matches panel: [h1 0..399 | zero 400..479]
  for (int e = tid; e < 15360; e += 256) {
    int i = e & 7, q = (e>>3)&3, row = (e>>5)&31, ks = e>>10;
    int k = ks*32 + q*8 + i;
    float v = 0.f;
    if (row < 30 && k < 400) v = p.wwin[(size_t)row*400 + k];
    wgM[e] = (_Float16)v;
  }
  for (int i = tid; i < 640; i += 256) kapS[i] = p.pkap[i];
  float bsum[4];
#pragma unroll
  for (int g = 0; g < 4; ++g) bsum[g] = p.bih1[g*400+u] + p.bhh1[g*400+u];
  float creg[2];
  creg[0] = p.c0[(size_t)bA*H_ + u];
  creg[1] = p.c0[(size_t)bB*H_ + u];
  __syncthreads();

  for (int t = 0; t < T_; ++t) {
    f32x4 acc0 = {0.f,0.f,0.f,0.f}, acc1 = {0.f,0.f,0.f,0.f};
    f32x4 am0  = {0.f,0.f,0.f,0.f}, am1  = {0.f,0.f,0.f,0.f};
    if (t > 0) wait_flags(p.flags, 0, t-1, G1); else __syncthreads();
    const u32* h1p = p.fh1 + (size_t)(t-1)*64*200;   // valid t>0
    // S0: rec pairs 0..79 -> panA
    {
      u32 tmp[20];
#pragma unroll
      for (int it = 0; it < 20; ++it) {
        int idx = tid + it*256; int b = idx/80, q = idx - b*80;
        if (t == 0) { float2 f = *(const float2*)(p.h0 + (size_t)b*H_ + 2*q); tmp[it] = pkf(f.x, f.y); }
        else tmp[it] = ldnt(&h1p[b*200 + q]);
      }
#pragma unroll
      for (int it = 0; it < 20; ++it) {
        int idx = tid + it*256; int b = idx/80, q = idx - b*80;
        ((u32*)panA)[b*92 + q] = tmp[it];
      }
    }
    __syncthreads();
    // S1: rec pairs 80..159 -> panB || M0 + Mw0 (panA: dims 0..159)
    {
      u32 tmp[20];
#pragma unroll
      for (int it = 0; it < 20; ++it) {
        int idx = tid + it*256; int b = idx/80, q = 80 + (idx - b*80);
        if (t == 0) { float2 f = *(const float2*)(p.h0 + (size_t)b*H_ + 2*q); tmp[it] = pkf(f.x, f.y); }
        else tmp[it] = ldnt(&h1p[b*200 + q]);
      }
      mfma_chunk5(panA, SW1, wgW, w, l, acc0, acc1);
      if (t > 0) mfma_chunk5(panA, SW1, wgM, w, l, am0, am1);
#pragma unroll
      for (int it = 0; it < 20; ++it) {
        int idx = tid + it*256; int b = idx/80, q = idx - b*80;
        ((u32*)panB)[b*92 + q] = tmp[it];
      }
    }
    __syncthreads();
    // S2: rec pairs 160..199 -> panA[0..39]; wv slot: t==0 real (pwv), t>0 zeros || M1 + Mw1 (panB)
    {
      u32 tmp[10], tw[10];
#pragma unroll
      for (int it = 0; it < 10; ++it) {
        int idx = tid + it*256; int b = idx/40, q = idx - b*40;
        if (t == 0) { float2 f = *(const float2*)(p.h0 + (size_t)b*H_ + 2*(160+q)); tmp[it] = pkf(f.x, f.y); }
        else tmp[it] = ldnt(&h1p[b*200 + 160 + q]);
        if (t == 0) {
          u32 v;
          if (q < 38)       v = pkf(p.pwv[(size_t)b*V_ + 2*q], p.pwv[(size_t)b*V_ + 2*q + 1]);
          else if (q == 38) v = pkf(p.pwv[(size_t)b*V_ + 76], p.x[((size_t)b*T_ + t)*3 + 0]);
          else              v = pkf(p.x[((size_t)b*T_ + t)*3 + 1], p.x[((size_t)b*T_ + t)*3 + 2]);
          tw[it] = v;
        } else tw[it] = 0u;
      }
      mfma_chunk5(panB, SW1, wgW + 5*1024, w, l, acc0, acc1);
      if (t > 0) mfma_chunk5(panB, SW1, wgM + 5*1024, w, l, am0, am1);
#pragma unroll
      for (int it = 0; it < 10; ++it) {
        int idx = tid + it*256; int b = idx/40, q = idx - b*40;
        ((u32*)panA)[b*92 + q] = tmp[it];
        ((u32*)panA)[b*92 + 40 + q] = tw[it];
      }
    }
    __syncthreads();
    if (t > 0) {
      // window phase: Mw2 (panA; wv slot zeros x zero weights) + zero wvs
      for (int i = tid; i < 4928; i += 256) wvs[i] = 0.f;
      mfma_chunk5(panA, SW1, wgM + 10*1024, w, l, am0, am1);
      // exp -> mixE, kappa update (unique owner per (b,m))
#pragma unroll
      for (int r = 0; r < 4; ++r) {
        int m = 16*(w&1) + (l>>4)*4 + r;
        if (m < 30) {
          float e0 = __expf(am0[r] + p.bwin[m]);
          float e1 = __expf(am1[r] + p.bwin[m]);
          mixE[bA*32 + m] = e0;
          mixE[bB*32 + m] = e1;
          if (m >= 20) { kapS[bA*10 + (m-20)] += e0; kapS[bB*10 + (m-20)] += e1; }
        }
      }
      __syncthreads();
      // phi + scatter -> wvs
      for (int c = tid; c < 3200; c += 256) {
        int b = c/50, uu = c - (c/50)*50;
        const float fu = (float)uu;
        float s = 0.f;
#pragma unroll
        for (int k = 0; k < 10; ++k) {
          float df = kapS[b*10+k] - fu;
          s += mixE[b*32+k] * __expf(-mixE[b*32+10+k]*df*df);
        }
        s *= p.tmask[(size_t)b*U_ + uu];
        atomicAdd(&wvs[b*77 + p.text[(size_t)b*U_ + uu]], s);
      }
      __syncthreads();
      // write wv+x pairs -> panA[40..79]
      for (int i = tid; i < 2560; i += 256) {
        int b = i/40, q = i - (i/40)*40;
        u32 v;
        if (q < 38)       v = pkf(wvs[b*77 + 2*q], wvs[b*77 + 2*q + 1]);
        else if (q == 38) v = pkf(wvs[b*77 + 76], p.x[((size_t)b*T_ + t)*3 + 0]);
        else              v = pkf(p.x[((size_t)b*T_ + t)*3 + 1], p.x[((size_t)b*T_ + t)*3 + 2]);
        ((u32*)panA)[b*92 + 40 + q] = v;
      }
      __syncthreads();
    }
    // M2(panA: dims 320..479)
    mfma_chunk5(panA, SW1, wgW + 10*1024, w, l, acc0, acc1);

    float hA, hB;
    {
      float cn = sigm(acc0[1]+bsum[1])*creg[0] + sigm(acc0[0]+bsum[0])*tanhf(acc0[2]+bsum[2]);
      creg[0] = cn; hA = sigm(acc0[3]+bsum[3])*tanhf(cn);
      float cn2 = sigm(acc1[1]+bsum[1])*creg[1] + sigm(acc1[0]+bsum[0])*tanhf(acc1[2]+bsum[2]);
      creg[1] = cn2; hB = sigm(acc1[3]+bsum[3])*tanhf(cn2);
    }
    {
      float hAp = __shfl_xor(hA, 16, 64);
      float hBp = __shfl_xor(hB, 16, 64);
      if (((l>>4) & 1) == 0) {
        const int pi = wg*4 + (ul>>1);
        stc_u(p.fh1 + ((size_t)t*64 + bA)*200 + pi, pkf(hA, hAp));
        stc_u(p.fh1 + ((size_t)t*64 + bB)*200 + pi, pkf(hB, hBp));
      }
    }
    __syncthreads();
    set_flag(p.flags, 0, t, wg);
  }
}

// ================= PA (attention) — 16 blocks x 4 batches; produces out_wv/out_kap/fwv =================
__device__ void pa_role(const P& p, int pa, char* smem) {
  const int tid = threadIdx.x;
  const int b0p = pa*4;
  u32* hsm    = (u32*)smem;                 // [4][200]
  float* mixP = (float*)(smem + 3200);      // 240
  float* mixL = (float*)(smem + 4160);      // 120
  float* kapL = (float*)(smem + 4640);      // 40
  float* wvs  = (float*)(smem + 4800);      // 308
  int* textL  = (int*)(smem + 6032);        // 200
  u32* wwf = p.wwf + (size_t)pa * WWFWG;
  for (int e = tid; e < 200*30; e += 256) {
    int kk = e / 30, m = e - (e/30)*30;
    wwf[(size_t)kk*32 + m] = pkf(p.wwin[(size_t)m*400 + 2*kk], p.wwin[(size_t)m*400 + 2*kk + 1]);
  }
  for (int i = tid; i < 200; i += 256)
    textL[i] = p.text[(size_t)(b0p + i/50)*U_ + (i - (i/50)*50)];
  float kap_reg = 0.f;
  if (tid < 120 && (tid % 30) >= 20)
    kap_reg = p.pkap[(size_t)(b0p + tid/30)*10 + (tid % 30 - 20)];
  __syncthreads();

  for (int t = 0; t < T_; ++t) {
    wait_flags(p.flags, 0, t, G1);
    for (int e = tid; e < 800; e += 256) {
      int bl = e / 200, q = e - bl*200;
      hsm[e] = ldnt(&p.fh1[((size_t)t*64 + b0p + bl)*200 + q]);
    }
    for (int i = tid; i < 308; i += 256) wvs[i] = 0.f;
    __syncthreads();
    if (tid < 240) {
      int pp = tid >> 1, h = tid & 1;
      int bl = pp / 30, m = pp - bl*30;
      const u32* hp = hsm + bl*200 + h*100;
      const u32* wp = wwf + (size_t)(h*100)*32 + m;
      float d0=0.f, d1=0.f, d2=0.f, d3=0.f;
#pragma unroll 4
      for (int kk = 0; kk < 100; kk += 4) {
        d0 = dot2(u2h(hp[kk]),   u2h(wp[(size_t)kk*32]),     d0);
        d1 = dot2(u2h(hp[kk+1]), u2h(wp[(size_t)(kk+1)*32]), d1);
        d2 = dot2(u2h(hp[kk+2]), u2h(wp[(size_t)(kk+2)*32]), d2);
        d3 = dot2(u2h(hp[kk+3]), u2h(wp[(size_t)(kk+3)*32]), d3);
      }
      mixP[tid] = (d0+d1)+(d2+d3);
    }
    __syncthreads();
    if (tid < 120) {
      int bl = tid / 30, m = tid - bl*30;
      float v = __expf(mixP[2*tid] + mixP[2*tid+1] + p.bwin[m]);
      mixL[tid] = v;
      if (m >= 20) {
        kap_reg += v;
        kapL[bl*10 + (m-20)] = kap_reg;
        if (t == T_-1) p.out_kap[(size_t)(b0p+bl)*10 + (m-20)] = kap_reg;
      }
    }
    __syncthreads();
    if (tid < 200) {
      int bl = tid / 50, uu = tid - bl*50;
      const float fu = (float)uu;
      float s = 0.f;
#pragma unroll
      for (int k = 0; k < 10; ++k) {
        float df = kapL[bl*10+k] - fu;
        s += mixL[bl*30+k] * __expf(-mixL[bl*30+10+k]*df*df);
      }
      s *= p.tmask[(size_t)(b0p+bl)*U_ + uu];
      atomicAdd(&wvs[bl*77 + textL[tid]], s);
    }
    __syncthreads();
    for (int i = tid; i < 308; i += 256) {
      int bl = i / 77, v = i - (i/77)*77;
      p.out_wv[((size_t)(b0p+bl)*T_ + t)*V_ + v] = wvs[i];
    }
    for (int i = tid; i < 160; i += 256) {
      int bl = i / 40, pr = i - (i/40)*40;
      int b = b0p + bl;
      float f0, f1;
      if (pr < 38)       { f0 = wvs[bl*77 + 2*pr]; f1 = wvs[bl*77 + 2*pr + 1]; }
      else if (pr == 38) { f0 = wvs[bl*77 + 76];   f1 = p.x[((size_t)b*T_ + t)*3 + 0]; }
      else               { f0 = p.x[((size_t)b*T_ + t)*3 + 1]; f1 = p.x[((size_t)b*T_ + t)*3 + 2]; }
      stc_u(p.fwv + ((size_t)t*64 + b)*40 + pr, pkf(f0, f1));
    }
    __syncthreads();
    set_flag(p.flags, 1, t, pa);
  }
}

// ---- L2/L3 staging: phase ph stages pairs [ph*112, ph*112+112) ----
__device__ __forceinline__ void stage_l23(u32* pan, int tid, int ph, int t,
    const u32* fwvt, const u32* hint, const u32* rect, const float* h0f) {
  u32 tmp[28];
#pragma unroll
  for (int it = 0; it < 28; ++it) {
    int idx = tid + it*256;
    int b = idx/112, pl = idx - b*112;
    int gp = ph*112 + pl;
    u32 v;
    if (gp < 40) v = ldnt(&fwvt[b*40 + gp]);
    else if (gp < 240) v = ldnt(&hint[b*200 + gp - 40]);
    else if (gp < 440) {
      if (t == 0) { float2 f = *(const float2*)(h0f + (size_t)b*H_ + 2*(gp-240)); v = pkf(f.x, f.y); }
      else v = ldnt(&rect[b*200 + gp - 240]);
    } else v = 0u;
    tmp[it] = v;
  }
#pragma unroll
  for (int it = 0; it < 28; ++it) {
    int idx = tid + it*256;
    int b = idx/112, pl = idx - b*112;
    pan[b*116 + pl] = tmp[it];
  }
}

// ================= L2/L3 =================
template <int L>
__device__ void lstm_role(const P& p, int wg, char* smem) {
  const int tid = threadIdx.x;
  const int w = tid >> 6, l = tid & 63;
  const int ul = (w&1)*4 + (l>>4);
  const int u  = wg*8 + ul;
  const int bA = (w>>1)*32 + (l&15), bB = bA + 16;
  constexpr int STG = (L==2) ? 2 : 3;
  _Float16* wgW = ((L==2) ? p.w2f : p.w3f) + (size_t)wg * W2WG;
  const float* wih = (L==2) ? p.wih2 : p.wih3;
  const float* whh = (L==2) ? p.whh2 : p.whh3;
  const float* bih = (L==2) ? p.bih2 : p.bih3;
  const float* bhh = (L==2) ? p.bhh2 : p.bhh3;
  const u32* hin = (L==2) ? p.fh1 : p.fh2;
  u32* rec = (L==2) ? p.fh2 : p.fh3;
  _Float16* panA = (_Float16*)smem;
  _Float16* panB = panA + 64*SW2;

  // prepack [ks28][row32][q4][i8]; K-order [wv77 | x3 | hin400 | rec400 | pad16]
  for (int e = tid; e < 28672; e += 256) {
    int i = e & 7, q = (e>>3)&3, row = (e>>5)&31, ks = e>>10;
    int k = ks*32 + q*8 + i;
    int cu = row>>2, g = row&3;
    int r = g*400 + wg*8 + cu;
    float v;
    if (k < 77)       v = wih[(size_t)r*480 + 403 + k];
    else if (k < 80)  v = wih[(size_t)r*480 + (k-77)];
    else if (k < 480) v = wih[(size_t)r*480 + 3 + (k-80)];
    else if (k < 880) v = whh[(size_t)r*400 + (k-480)];
    else              v = 0.f;
    wgW[e] = (_Float16)v;
  }
  float bsum[4];
#pragma unroll
  for (int g = 0; g < 4; ++g) bsum[g] = bih[g*400+u] + bhh[g*400+u];
  float creg[2];
  creg[0] = p.c0[(size_t)(L-1)*B_*H_ + (size_t)bA*H_ + u];
  creg[1] = p.c0[(size_t)(L-1)*B_*H_ + (size_t)bB*H_ + u];
  __syncthreads();

  for (int t = 0; t < T_; ++t) {
    f32x4 acc0 = {0.f,0.f,0.f,0.f}, acc1 = {0.f,0.f,0.f,0.f};
    if (L == 2) wait_flags(p.flags, 1, t, GPA);     // implies stage0(t)
    else        wait_flags(p.flags, 2, t, G2);
    const u32* fwvt = p.fwv + (size_t)t*64*40;
    const u32* hint = hin + (size_t)t*64*200;
    const u32* rect = rec + (size_t)(t-1)*64*200;   // valid t>0
    const float* h0f = p.h0 + (size_t)(L-1)*B_*H_;
    // S0 (wv+x+hin pairs 0..111) -> panA
    stage_l23((u32*)panA, tid, 0, t, fwvt, hint, rect, h0f);
    __syncthreads();
    // S1 (hin pairs 72..183 == gp 112..223) -> panB || M0(panA)
    {
      u32 tmp[28];
#pragma unroll
      for (int it = 0; it < 28; ++it) {
        int idx = tid + it*256;
        int b = idx/112, pl = idx - b*112;
        tmp[it] = ldnt(&hint[b*200 + 72 + pl]);   // gp = 112+pl -> hin pair gp-40
      }
      mfma_chunk7(panA, SW2, wgW, w, l, acc0, acc1);
#pragma unroll
      for (int it = 0; it < 28; ++it) {
        int idx = tid + it*256;
        int b = idx/112, pl = idx - b*112;
        ((u32*)panB)[b*116 + pl] = tmp[it];
      }
    }
    // own-rec wait (usually satisfied; placed after S1 so staging/M0 overlap it)
    if (t > 0) wait_flags(p.flags, STG, t-1, (L==2)?G2:G3); else __syncthreads();
    // S2 (hin tail + rec head) -> panA || M1(panB)
    {
      u32 tmp[28];
#pragma unroll
      for (int it = 0; it < 28; ++it) {
        int idx = tid + it*256;
        int b = idx/112, pl = idx - b*112;
        int gp = 224 + pl;
        u32 v;
        if (gp < 240) v = ldnt(&hint[b*200 + gp - 40]);
        else if (t == 0) { float2 f = *(const float2*)(h0f + (size_t)b*H_ + 2*(gp-240)); v = pkf(f.x, f.y); }
        else v = ldnt(&rect[b*200 + gp - 240]);
        tmp[it] = v;
      }
      mfma_chunk7(panB, SW2, wgW + 7*1024, w, l, acc0, acc1);
#pragma unroll
      for (int it = 0; it < 28; ++it) {
        int idx = tid + it*256;
        int b = idx/112, pl = idx - b*112;
        ((u32*)panA)[b*116 + pl] = tmp[it];
      }
    }
    __syncthreads();
    // S3 (rec tail + pad) -> panB || M2(panA)
    {
      u32 tmp[28];
#pragma unroll
      for (int it = 0; it < 28; ++it) {
        int idx = tid + it*256;
        int b = idx/112, pl = idx - b*112;
        int gp = 336 + pl;
        u32 v;
        if (gp < 440) {
          if (t == 0) { float2 f = *(const float2*)(h0f + (size_t)b*H_ + 2*(gp-240)); v = pkf(f.x, f.y); }
          else v = ldnt(&rect[b*200 + gp - 240]);
        } else v = 0u;
        tmp[it] = v;
      }
      mfma_chunk7(panA, SW2, wgW + 14*1024, w, l, acc0, acc1);
#pragma unroll
      for (int it = 0; it < 28; ++it) {
        int idx = tid + it*256;
        int b = idx/112, pl = idx - b*112;
        ((u32*)panB)[b*116 + pl] = tmp[it];
      }
    }
    __syncthreads();
    mfma_chunk7(panB, SW2, wgW + 21*1024, w, l, acc0, acc1);

    float hA, hB;
    {
      float cn = sigm(acc0[1]+bsum[1])*creg[0] + sigm(acc0[0]+bsum[0])*tanhf(acc0[2]+bsum[2]);
      creg[0] = cn; hA = sigm(acc0[3]+bsum[3])*tanhf(cn);
      float cn2 = sigm(acc1[1]+bsum[1])*creg[1] + sigm(acc1[0]+bsum[0])*tanhf(acc1[2]+bsum[2]);
      creg[1] = cn2; hB = sigm(acc1[3]+bsum[3])*tanhf(cn2);
    }
    {
      float hAp = __shfl_xor(hA, 16, 64);
      float hBp = __shfl_xor(hB, 16, 64);
      if (((l>>4) & 1) == 0) {
        const int pi = wg*4 + (ul>>1);
        stc_u(rec + ((size_t)t*64 + bA)*200 + pi, pkf(hA, hAp));
        stc_u(rec + ((size_t)t*64 + bB)*200 + pi, pkf(hB, hBp));
      }
    }
    __syncthreads();
    set_flag(p.flags, STG, t, wg);
  }
}

// ================= OUT =================
__device__ void out_role(const P& p, int g, char* smem) {
  const int tid = threadIdx.x;
  const int cg = tid & 31, bg = tid >> 5;
  const int c0 = cg*4;
  _Float16* pan = (_Float16*)smem;
  _Float16* wofg = p.wof + (size_t)g*WOWG;
  for (int e = tid; e < 300*32*16; e += 256) {
    int kk = e >> 9, rem = e & 511;
    int cgi = rem >> 4, j4 = rem & 15;
    int j = j4 >> 2, kc = j4 & 3;
    int c = cgi*4 + j; if (c > 120) c = 120;
    wofg[e] = (_Float16)p.wout[(size_t)c*1200 + kk*4 + kc];
  }
  float bo[4];
#pragma unroll
  for (int j = 0; j < 4; ++j) {
    int c = c0 + j; if (c > 120) c = 120;
    bo[j] = p.bout[c];
  }
  __syncthreads();

  for (int t = g; t < T_; t += GOUT) {
    wait_flags(p.flags, 3, t, G3);
    float acc[8][4];
#pragma unroll
    for (int r = 0; r < 8; ++r)
#pragma unroll
      for (int j = 0; j < 4; ++j) acc[r][j] = 0.f;

    for (int ph = 0; ph < 5; ++ph) {
      for (int idx = tid; idx < 7680; idx += 256) {
        int b = idx / 120, pl = idx - b*120;
        int Pp = ph*120 + pl;
        u32 pv;
        if (Pp < 200)      pv = ldnt(&p.fh1[((size_t)t*64 + b)*200 + Pp]);
        else if (Pp < 400) pv = ldnt(&p.fh2[((size_t)t*64 + b)*200 + (Pp-200)]);
        else               pv = ldnt(&p.fh3[((size_t)t*64 + b)*200 + (Pp-400)]);
        ((u32*)pan)[b*122 + pl] = pv;
      }
      __syncthreads();
      const _Float16* wp = wofg + ((size_t)(ph*60)*32 + cg)*16;
#pragma unroll 3
      for (int k = 0; k < 240; k += 4) {
        h4 wa = *(const h4*)(wp);
        h4 wb = *(const h4*)(wp+4);
        h4 wc = *(const h4*)(wp+8);
        h4 wd = *(const h4*)(wp+12);
        wp += 512;
#pragma unroll
        for (int r = 0; r < 8; ++r) {
          h4 a = *(const h4*)(pan + (bg*8+r)*SWO + k);
          h2 al = lo4(a), ah = hi4(a);
          acc[r][0] = dot2(al, lo4(wa), acc[r][0]); acc[r][0] = dot2(ah, hi4(wa), acc[r][0]);
          acc[r][1] = dot2(al, lo4(wb), acc[r][1]); acc[r][1] = dot2(ah, hi4(wb), acc[r][1]);
          acc[r][2] = dot2(al, lo4(wc), acc[r][2]); acc[r][2] = dot2(ah, hi4(wc), acc[r][2]);
          acc[r][3] = dot2(al, lo4(wd), acc[r][3]); acc[r][3] = dot2(ah, hi4(wd), acc[r][3]);
        }
      }
      __syncthreads();
    }
#pragma unroll
    for (int r = 0; r < 8; ++r)
#pragma unroll
      for (int j = 0; j < 4; ++j) {
        int c = c0 + j;
        if (c < 121)
          p.out_y[((size_t)(bg*8+r)*T_ + t)*OUT_ + c] = acc[r][j] + bo[j];
      }
    __syncthreads();
  }
}

__global__ __launch_bounds__(256) void hw_pipeline(P p) {
  __shared__ __align__(16) char smem_raw[SMEM_BYTES];
  const int bid = blockIdx.x;
  if (bid < G1) lstm1_role(p, bid, smem_raw);
  else if (bid < G1+GPA) pa_role(p, bid - G1, smem_raw);
  else if (bid < G1+GPA+G2) lstm_role<2>(p, bid - G1 - GPA, smem_raw);
  else if (bid < G1+GPA+G2+G3) lstm_role<3>(p, bid - G1 - GPA - G2, smem_raw);
  else out_role(p, bid - G1 - GPA - G2 - G3, smem_raw);
}

extern "C" void kernel_launch(void* const* d_in, const int* in_sizes, int n_in,
                              void* d_out, int out_size, void* d_ws, size_t ws_size,
                              hipStream_t stream) {
  (void)in_sizes; (void)n_in; (void)out_size; (void)ws_size;
  P p;
  p.x = (const float*)d_in[0];
  p.text = (const int*)d_in[1];
  p.tmask = (const float*)d_in[2];
  p.h0 = (const float*)d_in[3];
  p.c0 = (const float*)d_in[4];
  p.pwv = (const float*)d_in[5];
  p.pkap = (const float*)d_in[6];
  p.wih1 = (const float*)d_in[7];  p.whh1 = (const float*)d_in[8];
  p.bih1 = (const float*)d_in[9];  p.bhh1 = (const float*)d_in[10];
  p.wih2 = (const float*)d_in[11]; p.whh2 = (const float*)d_in[12];
  p.bih2 = (const float*)d_in[13]; p.bhh2 = (const float*)d_in[14];
  p.wih3 = (const float*)d_in[15]; p.whh3 = (const float*)d_in[16];
  p.bih3 = (const float*)d_in[17]; p.bhh3 = (const float*)d_in[18];
  p.wwin = (const float*)d_in[19]; p.bwin = (const float*)d_in[20];
  p.wout = (const float*)d_in[21]; p.bout = (const float*)d_in[22];
  float* out = (float*)d_out;
  p.out_y  = out;
  p.out_wv = out + (size_t)B_*T_*OUT_;
  p.out_kap = p.out_wv + (size_t)B_*T_*V_;
  char* ws = (char*)d_ws;
  p.flags = (u32*)(ws + FLAGS_B);
  p.w1f = (_Float16*)(ws + W1F_B);
  p.w2f = (_Float16*)(ws + W2F_B);
  p.w3f = (_Float16*)(ws + W3F_B);
  p.wof = (_Float16*)(ws + WOF_B);
  p.wwm = (_Float16*)(ws + WWM_B);
  p.wwf = (u32*)(ws + WWF_B);
  p.fwv = (u32*)(ws + FWV_B);
  p.fh1 = (u32*)(ws + FH1_B);
  p.fh2 = (u32*)(ws + FH2_B);
  p.fh3 = (u32*)(ws + FH3_B);
  (void)hipMemsetAsync(ws + FLAGS_B, 0, FLAGS_SZ, stream);
  hipLaunchKernelGGL(hw_pipeline, dim3(NBLK), dim3(256), 0, stream, p);
}

// Round 13
// 13597.368 us; speedup vs baseline: 1.6790x; 1.6790x over previous
//
#include <hip/hip_runtime.h>
#include <cstdint>
#include <cstddef>
#include <cstring>

using u32 = unsigned int;
typedef _Float16 h2 __attribute__((ext_vector_type(2)));
typedef _Float16 h4 __attribute__((ext_vector_type(4)));
typedef _Float16 h8 __attribute__((ext_vector_type(8)));
typedef float f32x4 __attribute__((ext_vector_type(4)));

constexpr int B_=64, T_=600, U_=50, V_=77, H_=400, OUT_=121;
constexpr int G1=50, GPA=16, G2=50, G3=50, GOUT=8;
constexpr int NBLK = G1+GPA+G2+G3+GOUT; // 174

// ---- ws byte offsets ----
constexpr size_t FLAGS_B = 0;                        // [stage4][t600][prod64] 16B slots
constexpr size_t FLAGS_SZ = 4ull*600*64*16;          // 2,457,600
// MFMA weight packs: [ks][row32][q4][i8] f16, row = unit_local*4 + gate
constexpr size_t W1WG   = 15ull*32*4*8;              // 15360 f16 (K=480)
constexpr size_t W1F_B  = FLAGS_SZ;
constexpr size_t W2WG   = 28ull*32*4*8;              // 28672 f16 (K=896 padded)
constexpr size_t W2F_B  = W1F_B + 50ull*W1WG*2;
constexpr size_t W3F_B  = W2F_B + 50ull*W2WG*2;
constexpr size_t WOWG   = 300ull*32*16;
constexpr size_t WOF_B  = W3F_B + 50ull*W2WG*2;
constexpr size_t WWFWG  = 200ull*32;                 // u32
constexpr size_t WWF_B  = WOF_B + 8ull*WOWG*2;
// mix MFMA packs for L1 in-block window: 50 × [ks15][row32][q4][i8]
constexpr size_t WWMWG  = 15ull*32*4*8;              // 15360 f16
constexpr size_t WWM_B  = WWF_B + 16ull*WWFWG*4;
// write-once, t-indexed inter-stage buffers — PAIR-MAJOR to kill false sharing:
// fh*: u32 [t600][pair200][batch64]; fwv: u32 [t600][pair40][batch64]
// producer block wg owns pairs [wg*4, wg*4+4) => 1KB contiguous exclusive lines.
constexpr size_t FWV_B  = WWM_B + 50ull*WWMWG*2;
constexpr size_t FH1_B  = FWV_B + 600ull*40*64*4;
constexpr size_t FH2_B  = FH1_B + 600ull*200*64*4;
constexpr size_t FH3_B  = FH2_B + 600ull*200*64*4;
constexpr int FH_T = 200*64;   // u32 per t
constexpr int FWV_T = 40*64;
// total ~112 MB

// LDS strides (f16 units) — 16B-aligned rows for ds_read_b128 B-fragments
constexpr int SW1 = 184;   // L1 panels (160 dims used, 92 u32 pairs)
constexpr int SW2 = 232;   // L2/L3 panels (224 dims used, 116 u32 pairs)
constexpr int SWO = 244;   // OUT (240 dims)
constexpr int SMEM_BYTES = 59392;   // L2 panels: 2*64*232*2
// L1 LDS layout: panA @0 (23552), panB @23552 (23552), kapS f32[640] @47104 (2560),
//                mixE f32[64][32] @49664 (8192); wvs f32[64][77] overlays panB

struct P {
  const float *x, *tmask, *h0, *c0, *pwv, *pkap;
  const int *text;
  const float *wih1,*whh1,*bih1,*bhh1;
  const float *wih2,*whh2,*bih2,*bhh2;
  const float *wih3,*whh3,*bih3,*bhh3;
  const float *wwin,*bwin,*wout,*bout;
  float *out_y,*out_wv,*out_kap;
  _Float16 *w1f,*w2f,*w3f,*wof,*wwm;
  u32 *wwf;
  u32 *fwv,*fh1,*fh2,*fh3;
  u32 *flags;
};

__device__ __forceinline__ u32 ldc_u(const u32* p) {
  return __hip_atomic_load((u32*)p, __ATOMIC_RELAXED, __HIP_MEMORY_SCOPE_AGENT);
}
__device__ __forceinline__ void stc_u(u32* p, u32 v) {
  __hip_atomic_store(p, v, __ATOMIC_RELAXED, __HIP_MEMORY_SCOPE_AGENT);
}
__device__ __forceinline__ float sigm(float x) { return 1.f/(1.f+__expf(-x)); }
__device__ __forceinline__ h2 pk16(float a, float b) {
  auto t = __builtin_amdgcn_cvt_pkrtz(a, b);
  h2 r; memcpy(&r, &t, 4); return r;
}
__device__ __forceinline__ u32 h2u(h2 v) { u32 r; memcpy(&r, &v, 4); return r; }
__device__ __forceinline__ h2 u2h(u32 v) { h2 r; memcpy(&r, &v, 4); return r; }
__device__ __forceinline__ u32 pkf(float a, float b) { return h2u(pk16(a, b)); }
__device__ __forceinline__ float dot2(h2 a, h2 b, float c) { return __builtin_amdgcn_fdot2(a, b, c, false); }
__device__ __forceinline__ h2 lo4(h4 v) { return __builtin_shufflevector(v, v, 0, 1); }
__device__ __forceinline__ h2 hi4(h4 v) { return __builtin_shufflevector(v, v, 2, 3); }

// ---- parallel per-producer flags (R9 proven form): n spinners, s_sleep backoff ----
__device__ __forceinline__ void wait_flags(u32* f, int stage, int t, int n) {
  if ((int)threadIdx.x < n) {
    const u32* s = f + (((size_t)stage*600 + t)*64 + threadIdx.x)*4;   // 16B slots
    while (ldc_u(s) == 0) __builtin_amdgcn_s_sleep(2);
  }
  __syncthreads();
}
__device__ __forceinline__ void set_flag(u32* f, int stage, int t, int prod) {
  if (threadIdx.x == 0)
    stc_u(f + (((size_t)stage*600 + t)*64 + prod)*4, 1u);
}

// ---- MFMA chunk: wave w computes 2 C-tiles (16 rows x 16 batches each) over KS k-steps
__device__ __forceinline__ void mfma_chunk5(const _Float16* pan, int SWf, const _Float16* WA,
                                            int w, int l, f32x4& acc0, f32x4& acc1) {
  const _Float16* bp0 = pan + ((w>>1)*32 + (l&15))*SWf + (l>>4)*8;
  const _Float16* bp1 = bp0 + 16*SWf;
  const _Float16* ap  = WA + (((16*(w&1) + (l&15))*4) + (l>>4))*8;
#pragma unroll
  for (int ks = 0; ks < 5; ++ks) {
    h8 a  = *(const h8*)(ap  + ks*1024);
    h8 b0 = *(const h8*)(bp0 + ks*32);
    h8 b1 = *(const h8*)(bp1 + ks*32);
    acc0 = __builtin_amdgcn_mfma_f32_16x16x32_f16(a, b0, acc0, 0, 0, 0);
    acc1 = __builtin_amdgcn_mfma_f32_16x16x32_f16(a, b1, acc1, 0, 0, 0);
  }
}
__device__ __forceinline__ void mfma_chunk7(const _Float16* pan, int SWf, const _Float16* WA,
                                            int w, int l, f32x4& acc0, f32x4& acc1) {
  const _Float16* bp0 = pan + ((w>>1)*32 + (l&15))*SWf + (l>>4)*8;
  const _Float16* bp1 = bp0 + 16*SWf;
  const _Float16* ap  = WA + (((16*(w&1) + (l&15))*4) + (l>>4))*8;
#pragma unroll
  for (int ks = 0; ks < 7; ++ks) {
    h8 a  = *(const h8*)(ap  + ks*1024);
    h8 b0 = *(const h8*)(bp0 + ks*32);
    h8 b1 = *(const h8*)(bp1 + ks*32);
    acc0 = __builtin_amdgcn_mfma_f32_16x16x32_f16(a, b0, acc0, 0, 0, 0);
    acc1 = __builtin_amdgcn_mfma_f32_16x16x32_f16(a, b1, acc1, 0, 0, 0);
  }
}

// ================= L1 (self-sufficient: in-block window via MFMA on staged panels) =================
__device__ void lstm1_role(const P& p, int wg, char* smem) {
  const int tid = threadIdx.x;
  const int w = tid >> 6, l = tid & 63;
  const int ul = (w&1)*4 + (l>>4);           // unit_local 0..7
  const int u  = wg*8 + ul;
  const int bA = (w>>1)*32 + (l&15), bB = bA + 16;
  _Float16* panA = (_Float16*)smem;
  _Float16* panB = panA + 64*SW1;
  float* kapS = (float*)(smem + 47104);      // [64][10] persistent kappa
  float* mixE = (float*)(smem + 49664);      // [64][32] exp(mix)
  float* wvs  = (float*)(smem + 23552);      // overlay panB: [64][77] f32
  _Float16* wgW = p.w1f + (size_t)wg * W1WG;
  _Float16* wgM = p.wwm + (size_t)wg * WWMWG;
  // gate pack [ks15][row32][q4][i8]; row = cu*4+g; K-order [rec400 | wv77 | x3]
  for (int e = tid; e < 15360; e += 256) {
    int i = e & 7, q = (e>>3)&3, row = (e>>5)&31, ks = e>>10;
    int k = ks*32 + q*8 + i;
    int cu = row>>2, g = row&3;
    int r = g*400 + wg*8 + cu;
    float v;
    if (k < 400)      v = p.whh1[(size_t)r*400 + k];
    else if (k < 477) v = p.wih1[(size_t)r*80 + 3 + (k-400)];
    else              v = p.wih1[(size_t)r*80 + (k-477)];
    wgW[e] = (_Float16)v;
  }
  // mix pack: row = m (30 used), K-order matches panel: [h1 0..399 | zero 400..479]
  for (int e = tid; e < 15360; e += 256) {
    int i = e & 7, q = (e>>3)&3, row = (e>>5)&31, ks = e>>10;
    int k = ks*32 + q*8 + i;
    float v = 0.f;
    if (row < 30 && k < 400) v = p.wwin[(size_t)row*400 + k];
    wgM[e] = (_Float16)v;
  }
  for (int i = tid; i < 640; i += 256) kapS[i] = p.pkap[i];
  float bsum[4];
#pragma unroll
  for (int g = 0; g < 4; ++g) bsum[g] = p.bih1[g*400+u] + p.bhh1[g*400+u];
  float creg[2];
  creg[0] = p.c0[(size_t)bA*H_ + u];
  creg[1] = p.c0[(size_t)bB*H_ + u];
  __syncthreads();

  for (int t = 0; t < T_; ++t) {
    f32x4 acc0 = {0.f,0.f,0.f,0.f}, acc1 = {0.f,0.f,0.f,0.f};
    f32x4 am0  = {0.f,0.f,0.f,0.f}, am1  = {0.f,0.f,0.f,0.f};
    if (t > 0) wait_flags(p.flags, 0, t-1, G1); else __syncthreads();
    const u32* h1p = p.fh1 + (size_t)(t-1)*FH_T;   // pair-major, valid t>0
    // S0: rec pairs 0..79 -> panA  (coalesced: lane->batch)
    {
      u32 tmp[20];
#pragma unroll
      for (int it = 0; it < 20; ++it) {
        int idx = tid + it*256; int q = idx>>6, b = idx&63;
        if (t == 0) { float2 f = *(const float2*)(p.h0 + (size_t)b*H_ + 2*q); tmp[it] = pkf(f.x, f.y); }
        else tmp[it] = h1p[q*64 + b];
      }
#pragma unroll
      for (int it = 0; it < 20; ++it) {
        int idx = tid + it*256; int q = idx>>6, b = idx&63;
        ((u32*)panA)[b*92 + q] = tmp[it];
      }
    }
    __syncthreads();
    // S1: rec pairs 80..159 -> panB || M0 + Mw0 (panA: dims 0..159)
    {
      u32 tmp[20];
#pragma unroll
      for (int it = 0; it < 20; ++it) {
        int idx = tid + it*256; int q = idx>>6, b = idx&63;
        if (t == 0) { float2 f = *(const float2*)(p.h0 + (size_t)b*H_ + 2*(80+q)); tmp[it] = pkf(f.x, f.y); }
        else tmp[it] = h1p[(80+q)*64 + b];
      }
      mfma_chunk5(panA, SW1, wgW, w, l, acc0, acc1);
      if (t > 0) mfma_chunk5(panA, SW1, wgM, w, l, am0, am1);
#pragma unroll
      for (int it = 0; it < 20; ++it) {
        int idx = tid + it*256; int q = idx>>6, b = idx&63;
        ((u32*)panB)[b*92 + q] = tmp[it];
      }
    }
    __syncthreads();
    // S2: rec pairs 160..199 -> panA[0..39]; wv slot: t==0 real (pwv), t>0 zeros || M1 + Mw1 (panB)
    {
      u32 tmp[10], tw[10];
#pragma unroll
      for (int it = 0; it < 10; ++it) {
        int idx = tid + it*256; int q = idx>>6, b = idx&63;
        if (t == 0) { float2 f = *(const float2*)(p.h0 + (size_t)b*H_ + 2*(160+q)); tmp[it] = pkf(f.x, f.y); }
        else tmp[it] = h1p[(160+q)*64 + b];
        if (t == 0) {
          u32 v;
          if (q < 38)       v = pkf(p.pwv[(size_t)b*V_ + 2*q], p.pwv[(size_t)b*V_ + 2*q + 1]);
          else if (q == 38) v = pkf(p.pwv[(size_t)b*V_ + 76], p.x[((size_t)b*T_ + t)*3 + 0]);
          else              v = pkf(p.x[((size_t)b*T_ + t)*3 + 1], p.x[((size_t)b*T_ + t)*3 + 2]);
          tw[it] = v;
        } else tw[it] = 0u;
      }
      mfma_chunk5(panB, SW1, wgW + 5*1024, w, l, acc0, acc1);
      if (t > 0) mfma_chunk5(panB, SW1, wgM + 5*1024, w, l, am0, am1);
#pragma unroll
      for (int it = 0; it < 10; ++it) {
        int idx = tid + it*256; int q = idx>>6, b = idx&63;
        ((u32*)panA)[b*92 + q] = tmp[it];
        ((u32*)panA)[b*92 + 40 + q] = tw[it];
      }
    }
    __syncthreads();
    if (t > 0) {
      // window phase: Mw2 (panA; wv slot zeros x zero weights) + zero wvs
      for (int i = tid; i < 4928; i += 256) wvs[i] = 0.f;
      mfma_chunk5(panA, SW1, wgM + 10*1024, w, l, am0, am1);
      // exp -> mixE, kappa update (unique owner per (b,m))
#pragma unroll
      for (int r = 0; r < 4; ++r) {
        int m = 16*(w&1) + (l>>4)*4 + r;
        if (m < 30) {
          float e0 = __expf(am0[r] + p.bwin[m]);
          float e1 = __expf(am1[r] + p.bwin[m]);
          mixE[bA*32 + m] = e0;
          mixE[bB*32 + m] = e1;
          if (m >= 20) { kapS[bA*10 + (m-20)] += e0; kapS[bB*10 + (m-20)] += e1; }
        }
      }
      __syncthreads();
      // phi + scatter -> wvs
      for (int c = tid; c < 3200; c += 256) {
        int b = c/50, uu = c - (c/50)*50;
        const float fu = (float)uu;
        float s = 0.f;
#pragma unroll
        for (int k = 0; k < 10; ++k) {
          float df = kapS[b*10+k] - fu;
          s += mixE[b*32+k] * __expf(-mixE[b*32+10+k]*df*df);
        }
        s *= p.tmask[(size_t)b*U_ + uu];
        atomicAdd(&wvs[b*77 + p.text[(size_t)b*U_ + uu]], s);
      }
      __syncthreads();
      // write wv+x pairs -> panA[40..79]
      for (int i = tid; i < 2560; i += 256) {
        int b = i/40, q = i - (i/40)*40;
        u32 v;
        if (q < 38)       v = pkf(wvs[b*77 + 2*q], wvs[b*77 + 2*q + 1]);
        else if (q == 38) v = pkf(wvs[b*77 + 76], p.x[((size_t)b*T_ + t)*3 + 0]);
        else              v = pkf(p.x[((size_t)b*T_ + t)*3 + 1], p.x[((size_t)b*T_ + t)*3 + 2]);
        ((u32*)panA)[b*92 + 40 + q] = v;
      }
      __syncthreads();
    }
    // M2(panA: dims 320..479)
    mfma_chunk5(panA, SW1, wgW + 10*1024, w, l, acc0, acc1);

    float hA, hB;
    {
      float cn = sigm(acc0[1]+bsum[1])*creg[0] + sigm(acc0[0]+bsum[0])*tanhf(acc0[2]+bsum[2]);
      creg[0] = cn; hA = sigm(acc0[3]+bsum[3])*tanhf(cn);
      float cn2 = sigm(acc1[1]+bsum[1])*creg[1] + sigm(acc1[0]+bsum[0])*tanhf(acc1[2]+bsum[2]);
      creg[1] = cn2; hB = sigm(acc1[3]+bsum[3])*tanhf(cn2);
    }
    {
      float hAp = __shfl_xor(hA, 16, 64);
      float hBp = __shfl_xor(hB, 16, 64);
      if (((l>>4) & 1) == 0) {
        const int pi = wg*4 + (ul>>1);
        stc_u(p.fh1 + (size_t)t*FH_T + pi*64 + bA, pkf(hA, hAp));
        stc_u(p.fh1 + (size_t)t*FH_T + pi*64 + bB, pkf(hB, hBp));
      }
    }
    __syncthreads();
    set_flag(p.flags, 0, t, wg);
  }
}

// ================= PA (attention) — 16 blocks x 4 batches; produces out_wv/out_kap/fwv =================
__device__ void pa_role(const P& p, int pa, char* smem) {
  const int tid = threadIdx.x;
  const int b0p = pa*4;
  u32* hsm    = (u32*)smem;                 // [4][200]
  float* mixP = (float*)(smem + 3200);      // 240
  float* mixL = (float*)(smem + 4160);      // 120
  float* kapL = (float*)(smem + 4640);      // 40
  float* wvs  = (float*)(smem + 4800);      // 308
  int* textL  = (int*)(smem + 6032);        // 200
  u32* wwf = p.wwf + (size_t)pa * WWFWG;
  for (int e = tid; e < 200*30; e += 256) {
    int kk = e / 30, m = e - (e/30)*30;
    wwf[(size_t)kk*32 + m] = pkf(p.wwin[(size_t)m*400 + 2*kk], p.wwin[(size_t)m*400 + 2*kk + 1]);
  }
  for (int i = tid; i < 200; i += 256)
    textL[i] = p.text[(size_t)(b0p + i/50)*U_ + (i - (i/50)*50)];
  float kap_reg = 0.f;
  if (tid < 120 && (tid % 30) >= 20)
    kap_reg = p.pkap[(size_t)(b0p + tid/30)*10 + (tid % 30 - 20)];
  __syncthreads();

  for (int t = 0; t < T_; ++t) {
    wait_flags(p.flags, 0, t, G1);
    for (int e = tid; e < 800; e += 256) {
      int q = e >> 2, bl = e & 3;
      hsm[bl*200 + q] = p.fh1[(size_t)t*FH_T + q*64 + b0p + bl];
    }
    for (int i = tid; i < 308; i += 256) wvs[i] = 0.f;
    __syncthreads();
    if (tid < 240) {
      int pp = tid >> 1, h = tid & 1;
      int bl = pp / 30, m = pp - bl*30;
      const u32* hp = hsm + bl*200 + h*100;
      const u32* wp = wwf + (size_t)(h*100)*32 + m;
      float d0=0.f, d1=0.f, d2=0.f, d3=0.f;
#pragma unroll 4
      for (int kk = 0; kk < 100; kk += 4) {
        d0 = dot2(u2h(hp[kk]),   u2h(wp[(size_t)kk*32]),     d0);
        d1 = dot2(u2h(hp[kk+1]), u2h(wp[(size_t)(kk+1)*32]), d1);
        d2 = dot2(u2h(hp[kk+2]), u2h(wp[(size_t)(kk+2)*32]), d2);
        d3 = dot2(u2h(hp[kk+3]), u2h(wp[(size_t)(kk+3)*32]), d3);
      }
      mixP[tid] = (d0+d1)+(d2+d3);
    }
    __syncthreads();
    if (tid < 120) {
      int bl = tid / 30, m = tid - bl*30;
      float v = __expf(mixP[2*tid] + mixP[2*tid+1] + p.bwin[m]);
      mixL[tid] = v;
      if (m >= 20) {
        kap_reg += v;
        kapL[bl*10 + (m-20)] = kap_reg;
        if (t == T_-1) p.out_kap[(size_t)(b0p+bl)*10 + (m-20)] = kap_reg;
      }
    }
    __syncthreads();
    if (tid < 200) {
      int bl = tid / 50, uu = tid - bl*50;
      const float fu = (float)uu;
      float s = 0.f;
#pragma unroll
      for (int k = 0; k < 10; ++k) {
        float df = kapL[bl*10+k] - fu;
        s += mixL[bl*30+k] * __expf(-mixL[bl*30+10+k]*df*df);
      }
      s *= p.tmask[(size_t)(b0p+bl)*U_ + uu];
      atomicAdd(&wvs[bl*77 + textL[tid]], s);
    }
    __syncthreads();
    for (int i = tid; i < 308; i += 256) {
      int bl = i / 77, v = i - (i/77)*77;
      p.out_wv[((size_t)(b0p+bl)*T_ + t)*V_ + v] = wvs[i];
    }
    for (int i = tid; i < 160; i += 256) {
      int pr = i >> 2, bl = i & 3;
      int b = b0p + bl;
      float f0, f1;
      if (pr < 38)       { f0 = wvs[bl*77 + 2*pr]; f1 = wvs[bl*77 + 2*pr + 1]; }
      else if (pr == 38) { f0 = wvs[bl*77 + 76];   f1 = p.x[((size_t)b*T_ + t)*3 + 0]; }
      else               { f0 = p.x[((size_t)b*T_ + t)*3 + 1]; f1 = p.x[((size_t)b*T_ + t)*3 + 2]; }
      stc_u(p.fwv + (size_t)t*FWV_T + pr*64 + b, pkf(f0, f1));
    }
    __syncthreads();
    set_flag(p.flags, 1, t, pa);
  }
}

// ---- L2/L3 staging: phase ph stages panel pairs [ph*112, ph*112+112) ----
// pair-major sources; lane->batch coalesced
__device__ __forceinline__ void stage_l23(u32* pan, int tid, int ph, int t,
    const u32* fwvt, const u32* hint, const u32* rect, const float* h0f) {
  u32 tmp[28];
#pragma unroll
  for (int it = 0; it < 28; ++it) {
    int idx = tid + it*256;
    int pl = idx>>6, b = idx&63;
    int gp = ph*112 + pl;
    u32 v;
    if (gp < 40) v = fwvt[gp*64 + b];
    else if (gp < 240) v = hint[(gp-40)*64 + b];
    else if (gp < 440) {
      if (t == 0) { float2 f = *(const float2*)(h0f + (size_t)b*H_ + 2*(gp-240)); v = pkf(f.x, f.y); }
      else v = rect[(gp-240)*64 + b];
    } else v = 0u;
    tmp[it] = v;
  }
#pragma unroll
  for (int it = 0; it < 28; ++it) {
    int idx = tid + it*256;
    int pl = idx>>6, b = idx&63;
    pan[b*116 + pl] = tmp[it];
  }
}

// ================= L2/L3 =================
template <int L>
__device__ void lstm_role(const P& p, int wg, char* smem) {
  const int tid = threadIdx.x;
  const int w = tid >> 6, l = tid & 63;
  const int ul = (w&1)*4 + (l>>4);
  const int u  = wg*8 + ul;
  const int bA = (w>>1)*32 + (l&15), bB = bA + 16;
  constexpr int STG = (L==2) ? 2 : 3;
  _Float16* wgW = ((L==2) ? p.w2f : p.w3f) + (size_t)wg * W2WG;
  const float* wih = (L==2) ? p.wih2 : p.wih3;
  const float* whh = (L==2) ? p.whh2 : p.whh3;
  const float* bih = (L==2) ? p.bih2 : p.bih3;
  const float* bhh = (L==2) ? p.bhh2 : p.bhh3;
  const u32* hin = (L==2) ? p.fh1 : p.fh2;
  u32* rec = (L==2) ? p.fh2 : p.fh3;
  _Float16* panA = (_Float16*)smem;
  _Float16* panB = panA + 64*SW2;

  // prepack [ks28][row32][q4][i8]; K-order [wv77 | x3 | hin400 | rec400 | pad16]
  for (int e = tid; e < 28672; e += 256) {
    int i = e & 7, q = (e>>3)&3, row = (e>>5)&31, ks = e>>10;
    int k = ks*32 + q*8 + i;
    int cu = row>>2, g = row&3;
    int r = g*400 + wg*8 + cu;
    float v;
    if (k < 77)       v = wih[(size_t)r*480 + 403 + k];
    else if (k < 80)  v = wih[(size_t)r*480 + (k-77)];
    else if (k < 480) v = wih[(size_t)r*480 + 3 + (k-80)];
    else if (k < 880) v = whh[(size_t)r*400 + (k-480)];
    else              v = 0.f;
    wgW[e] = (_Float16)v;
  }
  float bsum[4];
#pragma unroll
  for (int g = 0; g < 4; ++g) bsum[g] = bih[g*400+u] + bhh[g*400+u];
  float creg[2];
  creg[0] = p.c0[(size_t)(L-1)*B_*H_ + (size_t)bA*H_ + u];
  creg[1] = p.c0[(size_t)(L-1)*B_*H_ + (size_t)bB*H_ + u];
  __syncthreads();

  for (int t = 0; t < T_; ++t) {
    f32x4 acc0 = {0.f,0.f,0.f,0.f}, acc1 = {0.f,0.f,0.f,0.f};
    if (L == 2) wait_flags(p.flags, 1, t, GPA);     // implies stage0(t)
    else        wait_flags(p.flags, 2, t, G2);
    const u32* fwvt = p.fwv + (size_t)t*FWV_T;
    const u32* hint = hin + (size_t)t*FH_T;
    const u32* rect = rec + (size_t)(t-1)*FH_T;     // valid t>0
    const float* h0f = p.h0 + (size_t)(L-1)*B_*H_;
    // S0 (panel pairs 0..111 = wv40 + hin 0..71) -> panA
    stage_l23((u32*)panA, tid, 0, t, fwvt, hint, rect, h0f);
    __syncthreads();
    // S1 (panel pairs 112..223 = hin 72..183) -> panB || M0(panA)
    {
      u32 tmp[28];
#pragma unroll
      for (int it = 0; it < 28; ++it) {
        int idx = tid + it*256;
        int pl = idx>>6, b = idx&63;
        tmp[it] = hint[(72+pl)*64 + b];
      }
      mfma_chunk7(panA, SW2, wgW, w, l, acc0, acc1);
#pragma unroll
      for (int it = 0; it < 28; ++it) {
        int idx = tid + it*256;
        int pl = idx>>6, b = idx&63;
        ((u32*)panB)[b*116 + pl] = tmp[it];
      }
    }
    // own-rec wait (usually satisfied; placed after S1 so staging/M0 overlap it)
    if (t > 0) wait_flags(p.flags, STG, t-1, (L==2)?G2:G3); else __syncthreads();
    // S2 (panel pairs 224..335 = hin 184..199 + rec 0..95) -> panA || M1(panB)
    {
      u32 tmp[28];
#pragma unroll
      for (int it = 0; it < 28; ++it) {
        int idx = tid + it*256;
        int pl = idx>>6, b = idx&63;
        int gp = 224 + pl;
        u32 v;
        if (gp < 240) v = hint[(gp-40)*64 + b];
        else if (t == 0) { float2 f = *(const float2*)(h0f + (size_t)b*H_ + 2*(gp-240)); v = pkf(f.x, f.y); }
        else v = rect[(gp-240)*64 + b];
        tmp[it] = v;
      }
      mfma_chunk7(panB, SW2, wgW + 7*1024, w, l, acc0, acc1);
#pragma unroll
      for (int it = 0; it < 28; ++it) {
        int idx = tid + it*256;
        int pl = idx>>6, b = idx&63;
        ((u32*)panA)[b*116 + pl] = tmp[it];
      }
    }
    __syncthreads();
    // S3 (panel pairs 336..447 = rec 96..199 + pad) -> panB || M2(panA)
    {
      u32 tmp[28];
#pragma unroll
      for (int it = 0; it < 28; ++it) {
        int idx = tid + it*256;
        int pl = idx>>6, b = idx&63;
        int gp = 336 + pl;
        u32 v;
        if (gp < 440) {
          if (t == 0) { float2 f = *(const float2*)(h0f + (size_t)b*H_ + 2*(gp-240)); v = pkf(f.x, f.y); }
          else v = rect[(gp-240)*64 + b];
        } else v = 0u;
        tmp[it] = v;
      }
      mfma_chunk7(panA, SW2, wgW + 14*1024, w, l, acc0, acc1);
#pragma unroll
      for (int it = 0; it < 28; ++it) {
        int idx = tid + it*256;
        int pl = idx>>6, b = idx&63;
        ((u32*)panB)[b*116 + pl] = tmp[it];
      }
    }
    __syncthreads();
    mfma_chunk7(panB, SW2, wgW + 21*1024, w, l, acc0, acc1);

    float hA, hB;
    {
      float cn = sigm(acc0[1]+bsum[1])*creg[0] + sigm(acc0[0]+bsum[0])*tanhf(acc0[2]+bsum[2]);
      creg[0] = cn; hA = sigm(acc0[3]+bsum[3])*tanhf(cn);
      float cn2 = sigm(acc1[1]+bsum[1])*creg[1] + sigm(acc1[0]+bsum[0])*tanhf(acc1[2]+bsum[2]);
      creg[1] = cn2; hB = sigm(acc1[3]+bsum[3])*tanhf(cn2);
    }
    {
      float hAp = __shfl_xor(hA, 16, 64);
      float hBp = __shfl_xor(hB, 16, 64);
      if (((l>>4) & 1) == 0) {
        const int pi = wg*4 + (ul>>1);
        stc_u(rec + (size_t)t*FH_T + pi*64 + bA, pkf(hA, hAp));
        stc_u(rec + (size_t)t*FH_T + pi*64 + bB, pkf(hB, hBp));
      }
    }
    __syncthreads();
    set_flag(p.flags, STG, t, wg);
  }
}

// ================= OUT =================
__device__ void out_role(const P& p, int g, char* smem) {
  const int tid = threadIdx.x;
  const int cg = tid & 31, bg = tid >> 5;
  const int c0 = cg*4;
  _Float16* pan = (_Float16*)smem;
  _Float16* wofg = p.wof + (size_t)g*WOWG;
  for (int e = tid; e < 300*32*16; e += 256) {
    int kk = e >> 9, rem = e & 511;
    int cgi = rem >> 4, j4 = rem & 15;
    int j = j4 >> 2, kc = j4 & 3;
    int c = cgi*4 + j; if (c > 120) c = 120;
    wofg[e] = (_Float16)p.wout[(size_t)c*1200 + kk*4 + kc];
  }
  float bo[4];
#pragma unroll
  for (int j = 0; j < 4; ++j) {
    int c = c0 + j; if (c > 120) c = 120;
    bo[j] = p.bout[c];
  }
  __syncthreads();

  for (int t = g; t < T_; t += GOUT) {
    wait_flags(p.flags, 3, t, G3);
    float acc[8][4];
#pragma unroll
    for (int r = 0; r < 8; ++r)
#pragma unroll
      for (int j = 0; j < 4; ++j) acc[r][j] = 0.f;

    for (int ph = 0; ph < 5; ++ph) {
      for (int idx = tid; idx < 7680; idx += 256) {
        int pl = idx>>6, b = idx&63;
        int Pp = ph*120 + pl;
        u32 pv;
        if (Pp < 200)      pv = p.fh1[(size_t)t*FH_T + Pp*64 + b];
        else if (Pp < 400) pv = p.fh2[(size_t)t*FH_T + (Pp-200)*64 + b];
        else               pv = p.fh3[(size_t)t*FH_T + (Pp-400)*64 + b];
        ((u32*)pan)[b*122 + pl] = pv;
      }
      __syncthreads();
      const _Float16* wp = wofg + ((size_t)(ph*60)*32 + cg)*16;
#pragma unroll 3
      for (int k = 0; k < 240; k += 4) {
        h4 wa = *(const h4*)(wp);
        h4 wb = *(const h4*)(wp+4);
        h4 wc = *(const h4*)(wp+8);
        h4 wd = *(const h4*)(wp+12);
        wp += 512;
#pragma unroll
        for (int r = 0; r < 8; ++r) {
          h4 a = *(const h4*)(pan + (bg*8+r)*SWO + k);
          h2 al = lo4(a), ah = hi4(a);
          acc[r][0] = dot2(al, lo4(wa), acc[r][0]); acc[r][0] = dot2(ah, hi4(wa), acc[r][0]);
          acc[r][1] = dot2(al, lo4(wb), acc[r][1]); acc[r][1] = dot2(ah, hi4(wb), acc[r][1]);
          acc[r][2] = dot2(al, lo4(wc), acc[r][2]); acc[r][2] = dot2(ah, hi4(wc), acc[r][2]);
          acc[r][3] = dot2(al, lo4(wd), acc[r][3]); acc[r][3] = dot2(ah, hi4(wd), acc[r][3]);
        }
      }
      __syncthreads();
    }
#pragma unroll
    for (int r = 0; r < 8; ++r)
#pragma unroll
      for (int j = 0; j < 4; ++j) {
        int c = c0 + j;
        if (c < 121)
          p.out_y[((size_t)(bg*8+r)*T_ + t)*OUT_ + c] = acc[r][j] + bo[j];
      }
    __syncthreads();
  }
}

__global__ __launch_bounds__(256) void hw_pipeline(P p) {
  __shared__ __align__(16) char smem_raw[SMEM_BYTES];
  const int bid = blockIdx.x;
  if (bid < G1) lstm1_role(p, bid, smem_raw);
  else if (bid < G1+GPA) pa_role(p, bid - G1, smem_raw);
  else if (bid < G1+GPA+G2) lstm_role<2>(p, bid - G1 - GPA, smem_raw);
  else if (bid < G1+GPA+G2+G3) lstm_role<3>(p, bid - G1 - GPA - G2, smem_raw);
  else out_role(p, bid - G1 - GPA - G2 - G3, smem_raw);
}

extern "C" void kernel_launch(void* const* d_in, const int* in_sizes, int n_in,
                              void* d_out, int out_size, void* d_ws, size_t ws_size,
                              hipStream_t stream) {
  (void)in_sizes; (void)n_in; (void)out_size; (void)ws_size;
  P p;
  p.x = (const float*)d_in[0];
  p.text = (const int*)d_in[1];
  p.tmask = (const float*)d_in[2];
  p.h0 = (const float*)d_in[3];
  p.c0 = (const float*)d_in[4];
  p.pwv = (const float*)d_in[5];
  p.pkap = (const float*)d_in[6];
  p.wih1 = (const float*)d_in[7];  p.whh1 = (const float*)d_in[8];
  p.bih1 = (const float*)d_in[9];  p.bhh1 = (const float*)d_in[10];
  p.wih2 = (const float*)d_in[11]; p.whh2 = (const float*)d_in[12];
  p.bih2 = (const float*)d_in[13]; p.bhh2 = (const float*)d_in[14];
  p.wih3 = (const float*)d_in[15]; p.whh3 = (const float*)d_in[16];
  p.bih3 = (const float*)d_in[17]; p.bhh3 = (const float*)d_in[18];
  p.wwin = (const float*)d_in[19]; p.bwin = (const float*)d_in[20];
  p.wout = (const float*)d_in[21]; p.bout = (const float*)d_in[22];
  float* out = (float*)d_out;
  p.out_y  = out;
  p.out_wv = out + (size_t)B_*T_*OUT_;
  p.out_kap = p.out_wv + (size_t)B_*T_*V_;
  char* ws = (char*)d_ws;
  p.flags = (u32*)(ws + FLAGS_B);
  p.w1f = (_Float16*)(ws + W1F_B);
  p.w2f = (_Float16*)(ws + W2F_B);
  p.w3f = (_Float16*)(ws + W3F_B);
  p.wof = (_Float16*)(ws + WOF_B);
  p.wwm = (_Float16*)(ws + WWM_B);
  p.wwf = (u32*)(ws + WWF_B);
  p.fwv = (u32*)(ws + FWV_B);
  p.fh1 = (u32*)(ws + FH1_B);
  p.fh2 = (u32*)(ws + FH2_B);
  p.fh3 = (u32*)(ws + FH3_B);
  (void)hipMemsetAsync(ws + FLAGS_B, 0, FLAGS_SZ, stream);
  hipLaunchKernelGGL(hw_pipeline, dim3(NBLK), dim3(256), 0, stream, p);
}